// Round 8
// baseline (450.402 us; speedup 1.0000x reference)
//
#include <hip/hip_runtime.h>
#include <cstdint>
#include <cstddef>

// Problem constants: B=4, T=2048, H=1024, NH=16, HD=64, FF=4096, M=B*T=8192
typedef unsigned short u16;
typedef __attribute__((ext_vector_type(8))) __bf16 bf16x8;
typedef __attribute__((ext_vector_type(4))) __bf16 bf16x4;
typedef __attribute__((ext_vector_type(4))) float f32x4;
typedef __attribute__((ext_vector_type(4))) u16 u16x4;

#define MFMA(a, b, c) __builtin_amdgcn_mfma_f32_16x16x32_bf16((a), (b), (c), 0, 0, 0)

__device__ __forceinline__ u16 f2b(float f) {  // native RNE cvt (1-2 ops)
  union { __bf16 h; u16 u; } v;
  v.h = (__bf16)f;
  return v.u;
}

__device__ __forceinline__ void gld16(const void* g, void* l) {
  __builtin_amdgcn_global_load_lds(
      (__attribute__((address_space(1))) void*)(void*)(g),
      (__attribute__((address_space(3))) void*)(l), 16, 0, 0);
}

// Fragment-ordered layouts (per head, 131072 u16 = 2048x64):
__device__ __forceinline__ size_t qk_off(int t, int hd) {
  return (size_t)((((t >> 4) * 2 + (hd >> 5)) * 512)
                  + ((((hd >> 3) & 3) * 16 + (t & 15)) * 8) + (hd & 7));
}
__device__ __forceinline__ size_t v_off(int t, int hd) {
  int kk = ((t & 15) << 2) | ((t >> 4) & 3);
  return (size_t)(((t >> 6) * 4096)
                  + (((hd >> 4) * 2 + (kk >> 5)) * 512)
                  + ((((kk >> 3) & 3) * 16 + (hd & 15)) * 8) + (kk & 7));
}

// ---------------------------------------------------------------------------
// prep: xconv (fp32->bf16) + all weight transposes in ONE launch.
// blocks 0..8191: xconv (x -> xb, vectorized x4).
// blocks 8192..19455: wtrans sections (Wq/Wk/Wv | W1 | W2) -> bf16 transposed.
__global__ void prep(const float* __restrict__ x, u16* __restrict__ xb,
                     const float* __restrict__ Wq, const float* __restrict__ Wk,
                     const float* __restrict__ Wv, const float* __restrict__ W1,
                     const float* __restrict__ W2, u16* __restrict__ Wqkvt,
                     u16* __restrict__ W1t, u16* __restrict__ W2t) {
  int blk = blockIdx.x;
  int tx = threadIdx.x, ty = threadIdx.y;
  if (blk < 8192) {
    int i = (blk * 256 + ty * 32 + tx) * 4;
    float4 v = *(const float4*)(x + i);
    u16x4 o;
    o[0] = f2b(v.x); o[1] = f2b(v.y); o[2] = f2b(v.z); o[3] = f2b(v.w);
    *(u16x4*)(xb + i) = o;
    return;
  }
  blk -= 8192;
  __shared__ float tile[32][33];
  const float* W;
  u16* Wt;
  int Kd, Nd, nx;
  if (blk < 3072) {
    int s = blk >> 10;
    blk &= 1023;
    W = (s == 0) ? Wq : (s == 1) ? Wk : Wv;
    Wt = Wqkvt + (size_t)s * 1048576;
    Kd = 1024; Nd = 1024; nx = 32;
  } else if (blk < 7168) {
    blk -= 3072; W = W1; Wt = W1t; Kd = 1024; Nd = 4096; nx = 128;
  } else {
    blk -= 7168; W = W2; Wt = W2t; Kd = 4096; Nd = 1024; nx = 32;
  }
  int n0 = (blk % nx) * 32, k0 = (blk / nx) * 32;
#pragma unroll
  for (int i = 0; i < 4; i++)
    tile[ty + i * 8][tx] = W[(size_t)(k0 + ty + i * 8) * Nd + n0 + tx];
  __syncthreads();
#pragma unroll
  for (int i = 0; i < 4; i++)
    Wt[(size_t)(n0 + ty + i * 8) * Kd + k0 + tx] = f2b(tile[tx][ty + i * 8]);
}

// ---------------------------------------------------------------------------
// 256x256 8-phase COUNTED-vmcnt GEMM, PERSISTENT over 2 bn-tiles.
// BK=64, 8 waves; quadrant (mh,nh) selects the operand half; gray-coded
// phase order (0,0),(0,1),(1,1),(1,0) frees A0 after ph1, B1 after ph2.
// Staging: ph0 A1(t+1), ph1 B0(t+1), ph2 A0(t+2)->buf[t], ph3 B1(t+2)->buf[t].
// End-of-tile vmcnt(4): only A0/B1(t+2) in flight; never drains mid-loop.
// PERSISTENT (R7->R8): grid 256; block does bn = bnp and bnp+8 for its bm.
// After rep-0's final drain, rep-1's 12 prologue loads are ISSUED BEFORE the
// epilogue (fill hides under the 128KB store burst); rep-1 starts at
// vmcnt(4) (the 12 loads are the oldest outstanding VM ops -> <=4 outstanding
// implies tile-0 landed). A-panel staged twice but L2-hot on rep 1.
// XCD map: xcd owns bm in [4xcd, 4xcd+4); per-xcd 32 blocks = 4bm x 8bnp.
// MODE 2: bf16 out = gelu(v). Requires M=8192 (nbm=32), N=4096 (nbn=16).
template <int MODE>
__global__ __launch_bounds__(512, 2) void gemm8p(
    const u16* __restrict__ A, const u16* __restrict__ Bt,
    const float* __restrict__ b0, void* __restrict__ outp,
    int N, int K) {
  __shared__ __attribute__((aligned(16))) u16 As_[2][16384];
  __shared__ __attribute__((aligned(16))) u16 Bs_[2][16384];
  const int tid = threadIdx.x;
  const int wid = tid >> 6, lane = tid & 63;
  const int g = lane >> 4, r = lane & 15;

  const int xcd = blockIdx.x & 7;
  const int ii = blockIdx.x >> 3;       // 0..31 per xcd
  const int bm = xcd * 4 + (ii >> 3);
  const int bnp = ii & 7;               // bn = bnp + rep*8

  const int mrow = (wid >> 2) * 64;   // wave's 64-row band within each A-half
  const int ncol = (wid & 3) * 32;    // wave's 32-col band within each B-half

  const int ko0 = ((0 * 4 + g) ^ (r & 7)) * 8;
  const int ko1 = ((1 * 4 + g) ^ (r & 7)) * 8;

  // staging source offsets (u16 elems); row/chunk XOR-swizzled both sides.
  size_t aOff[4];
  int arow_[4], js_[4];
#pragma unroll
  for (int i4 = 0; i4 < 4; i4++) {
    int cc = i4 * 512 + tid, row = cc >> 3;
    int js = ((cc & 7) ^ (row & 7)) * 8;
    arow_[i4] = row; js_[i4] = js;
    aOff[i4] = (size_t)(bm * 256 + row) * K + js;
  }

  const int KT = K >> 6;

  for (int rep = 0; rep < 2; ++rep) {
    const int bn = bnp + rep * 8;
    size_t bOff[4];
#pragma unroll
    for (int i4 = 0; i4 < 4; i4++)
      bOff[i4] = (size_t)(bn * 256 + arow_[i4]) * K + js_[i4];

    f32x4 acc[8][4];
    const f32x4 zero4 = {0.f, 0.f, 0.f, 0.f};
#pragma unroll
    for (int i = 0; i < 8; i++)
#pragma unroll
      for (int j = 0; j < 4; j++) acc[i][j] = zero4;

    if (rep == 0) {
      // prologue: all 4 units of tile 0 -> buf0; A0(1), B1(1) -> buf1
#pragma unroll
      for (int i4 = 0; i4 < 4; i4++) {
        gld16(A + aOff[i4], &As_[0][(i4 * 512 + tid) * 8]);
        gld16(Bt + bOff[i4], &Bs_[0][(i4 * 512 + tid) * 8]);
      }
      gld16(A + aOff[0] + 64, &As_[1][(0 * 512 + tid) * 8]);
      gld16(A + aOff[1] + 64, &As_[1][(1 * 512 + tid) * 8]);
      gld16(Bt + bOff[2] + 64, &Bs_[1][(2 * 512 + tid) * 8]);
      gld16(Bt + bOff[3] + 64, &Bs_[1][(3 * 512 + tid) * 8]);
    }
    // rep 1: prologue was issued before rep 0's epilogue.
    asm volatile("s_waitcnt vmcnt(4)" ::: "memory");  // tile 0 landed
    __builtin_amdgcn_s_barrier();

    for (int t = 0; t < KT; ++t) {
      const int p = t & 1, pn = p ^ 1;
      const u16* as = As_[p];
      const u16* bs = Bs_[p];
      const bool m1 = (t + 1) < KT, m2 = (t + 2) < KT;
      const size_t k1 = (size_t)(t + 1) * 64, k2 = (size_t)(t + 2) * 64;
      bf16x8 af[4][2], bf[2][2];

      // ---- phase 0: (mh0, nh0); stage A1(t+1) ----
#pragma unroll
      for (int mt = 0; mt < 4; mt++) {
        int rw = mrow + mt * 16 + r;
        af[mt][0] = *(const bf16x8*)&as[rw * 64 + ko0];
        af[mt][1] = *(const bf16x8*)&as[rw * 64 + ko1];
      }
#pragma unroll
      for (int nt = 0; nt < 2; nt++) {
        int rw = ncol + nt * 16 + r;
        bf[nt][0] = *(const bf16x8*)&bs[rw * 64 + ko0];
        bf[nt][1] = *(const bf16x8*)&bs[rw * 64 + ko1];
      }
      if (m1) {
        gld16(A + aOff[2] + k1, &As_[pn][(1024 + tid) * 8]);
        gld16(A + aOff[3] + k1, &As_[pn][(1536 + tid) * 8]);
      }
      __builtin_amdgcn_s_barrier();
      asm volatile("s_waitcnt lgkmcnt(0)" ::: "memory");
      __builtin_amdgcn_sched_barrier(0);
      __builtin_amdgcn_s_setprio(1);
#pragma unroll
      for (int mt = 0; mt < 4; mt++)
#pragma unroll
        for (int nt = 0; nt < 2; nt++)
          acc[mt][nt] = MFMA(af[mt][1], bf[nt][1], MFMA(af[mt][0], bf[nt][0], acc[mt][nt]));
      __builtin_amdgcn_s_setprio(0);
      __builtin_amdgcn_s_barrier();

      // ---- phase 1: (mh0, nh1); stage B0(t+1) ----
#pragma unroll
      for (int nt = 0; nt < 2; nt++) {
        int rw = 128 + ncol + nt * 16 + r;
        bf[nt][0] = *(const bf16x8*)&bs[rw * 64 + ko0];
        bf[nt][1] = *(const bf16x8*)&bs[rw * 64 + ko1];
      }
      if (m1) {
        gld16(Bt + bOff[0] + k1, &Bs_[pn][(tid) * 8]);
        gld16(Bt + bOff[1] + k1, &Bs_[pn][(512 + tid) * 8]);
      }
      __builtin_amdgcn_s_barrier();
      asm volatile("s_waitcnt lgkmcnt(0)" ::: "memory");
      __builtin_amdgcn_sched_barrier(0);
      __builtin_amdgcn_s_setprio(1);
#pragma unroll
      for (int mt = 0; mt < 4; mt++)
#pragma unroll
        for (int nt = 0; nt < 2; nt++)
          acc[mt][2 + nt] = MFMA(af[mt][1], bf[nt][1], MFMA(af[mt][0], bf[nt][0], acc[mt][2 + nt]));
      __builtin_amdgcn_s_setprio(0);
      __builtin_amdgcn_s_barrier();   // A0 region of buf[p] now free

      // ---- phase 2: (mh1, nh1); stage A0(t+2) into buf[p] ----
#pragma unroll
      for (int mt = 0; mt < 4; mt++) {
        int rw = 128 + mrow + mt * 16 + r;
        af[mt][0] = *(const bf16x8*)&as[rw * 64 + ko0];
        af[mt][1] = *(const bf16x8*)&as[rw * 64 + ko1];
      }
      if (m2) {
        gld16(A + aOff[0] + k2, &As_[p][(tid) * 8]);
        gld16(A + aOff[1] + k2, &As_[p][(512 + tid) * 8]);
      }
      __builtin_amdgcn_s_barrier();
      asm volatile("s_waitcnt lgkmcnt(0)" ::: "memory");
      __builtin_amdgcn_sched_barrier(0);
      __builtin_amdgcn_s_setprio(1);
#pragma unroll
      for (int mt = 0; mt < 4; mt++)
#pragma unroll
        for (int nt = 0; nt < 2; nt++)
          acc[4 + mt][2 + nt] = MFMA(af[mt][1], bf[nt][1], MFMA(af[mt][0], bf[nt][0], acc[4 + mt][2 + nt]));
      __builtin_amdgcn_s_setprio(0);
      __builtin_amdgcn_s_barrier();   // B1 region of buf[p] now free

      // ---- phase 3: (mh1, nh0); stage B1(t+2) into buf[p] ----
#pragma unroll
      for (int nt = 0; nt < 2; nt++) {
        int rw = ncol + nt * 16 + r;
        bf[nt][0] = *(const bf16x8*)&bs[rw * 64 + ko0];
        bf[nt][1] = *(const bf16x8*)&bs[rw * 64 + ko1];
      }
      if (m2) {
        gld16(Bt + bOff[2] + k2, &Bs_[p][(1024 + tid) * 8]);
        gld16(Bt + bOff[3] + k2, &Bs_[p][(1536 + tid) * 8]);
      }
      __builtin_amdgcn_s_barrier();
      asm volatile("s_waitcnt lgkmcnt(0)" ::: "memory");
      __builtin_amdgcn_sched_barrier(0);
      __builtin_amdgcn_s_setprio(1);
#pragma unroll
      for (int mt = 0; mt < 4; mt++)
#pragma unroll
        for (int nt = 0; nt < 2; nt++)
          acc[4 + mt][nt] = MFMA(af[mt][1], bf[nt][1], MFMA(af[mt][0], bf[nt][0], acc[4 + mt][nt]));
      __builtin_amdgcn_s_setprio(0);
      if (m2) asm volatile("s_waitcnt vmcnt(4)" ::: "memory");
      else    asm volatile("s_waitcnt vmcnt(0)" ::: "memory");
      __builtin_amdgcn_s_barrier();
    }

    // issue next rep's prologue BEFORE the epilogue: the 12 loads' latency
    // hides under the 128KB store burst. All LDS reads of this rep completed
    // before the final vmcnt(0)+barrier above -> safe to overwrite buffers.
    if (rep == 0) {
      const int bn1 = bnp + 8;
      size_t bOff1;
#pragma unroll
      for (int i4 = 0; i4 < 4; i4++) {
        bOff1 = (size_t)(bn1 * 256 + arow_[i4]) * K + js_[i4];
        gld16(A + aOff[i4], &As_[0][(i4 * 512 + tid) * 8]);
        gld16(Bt + bOff1, &Bs_[0][(i4 * 512 + tid) * 8]);
      }
      gld16(A + aOff[0] + 64, &As_[1][(0 * 512 + tid) * 8]);
      gld16(A + aOff[1] + 64, &As_[1][(1 * 512 + tid) * 8]);
      gld16(Bt + (size_t)(bn1 * 256 + arow_[2]) * K + js_[2] + 64,
            &Bs_[1][(2 * 512 + tid) * 8]);
      gld16(Bt + (size_t)(bn1 * 256 + arow_[3]) * K + js_[3] + 64,
            &Bs_[1][(3 * 512 + tid) * 8]);
    }

    // epilogue: row = bm*256 + mh*128 + mrow + mt*16 + g*4 + q,
    //           col = bn*256 + nh*128 + ncol + nt*16 + r
#pragma unroll
    for (int am = 0; am < 8; am++) {
#pragma unroll
      for (int an = 0; an < 4; an++) {
        int col = bn * 256 + (an >> 1) * 128 + ncol + (an & 1) * 16 + r;
        float bv = b0[col];
#pragma unroll
        for (int q = 0; q < 4; q++) {
          int row = bm * 256 + (am >> 2) * 128 + mrow + (am & 3) * 16 + g * 4 + q;
          float v = acc[am][an][q] + bv;
          if (MODE == 2) {
            const float c1 = -2.3025850929940457f;
            const float c2 = c1 * 0.044715f;
            float t2 = v * v;
            float z = v * (c1 + c2 * t2);
            float sg = 1.0f / (1.0f + __builtin_amdgcn_exp2f(z));
            ((u16*)outp)[(size_t)row * N + col] = f2b(v * sg);
          }
        }
      }
    }
  }
}

// ---------------------------------------------------------------------------
// 256x128 3-buffer counted-vmcnt GEMM, barrier-light K-loop (R3 winner).
// acc[4][4] = 64 AGPRs: register headroom for the MODE-4 scatter epilogue.
// MODE 3: fp32 out = v + resid   MODE 4: fused QKV scatter (frag-order)
template <int MODE>
__global__ __launch_bounds__(512, 2) void gemm256(
    const u16* __restrict__ A, const u16* __restrict__ Bt,
    const float* __restrict__ b0, const float* __restrict__ b1,
    const float* __restrict__ b2, void* __restrict__ outp,
    const float* __restrict__ resid, int N, int K, float scale) {
  __shared__ __attribute__((aligned(16))) u16 As_[3][16384];
  __shared__ __attribute__((aligned(16))) u16 Bs_[3][8192];
  const int tid = threadIdx.x;
  const int wid = tid >> 6, lane = tid & 63;
  const int g = lane >> 4, r = lane & 15;

  const int xcd = blockIdx.x & 7;
  const int ii = blockIdx.x >> 3;
  const int bm = xcd * 4 + ((ii & 31) >> 3);
  const int bn = (ii >> 5) * 8 + (ii & 7);

  const int wrow = (wid >> 1) * 64;   // 4 M-waves
  const int wcol = (wid & 1) * 64;    // 2 N-waves

  const int ko0 = ((0 * 4 + g) ^ (r & 7)) * 8;
  const int ko1 = ((1 * 4 + g) ^ (r & 7)) * 8;

  size_t aOff[4], bOff[2];
#pragma unroll
  for (int i4 = 0; i4 < 4; i4++) {
    int cc = i4 * 512 + tid, row = cc >> 3;
    int js = ((cc & 7) ^ (row & 7)) * 8;
    aOff[i4] = (size_t)(bm * 256 + row) * K + js;
  }
#pragma unroll
  for (int i2 = 0; i2 < 2; i2++) {
    int cc = i2 * 512 + tid, row = cc >> 3;
    int js = ((cc & 7) ^ (row & 7)) * 8;
    bOff[i2] = (size_t)(bn * 128 + row) * K + js;
  }

  f32x4 acc[4][4];
  const f32x4 zero4 = {0.f, 0.f, 0.f, 0.f};
#pragma unroll
  for (int i = 0; i < 4; i++)
#pragma unroll
    for (int j = 0; j < 4; j++) acc[i][j] = zero4;

  // prologue: stage tiles 0 and 1; wait for tile 0 only (tile 1 in flight)
#pragma unroll
  for (int i4 = 0; i4 < 4; i4++) gld16(A + aOff[i4], &As_[0][(i4 * 512 + tid) * 8]);
#pragma unroll
  for (int i2 = 0; i2 < 2; i2++) gld16(Bt + bOff[i2], &Bs_[0][(i2 * 512 + tid) * 8]);
#pragma unroll
  for (int i4 = 0; i4 < 4; i4++) gld16(A + aOff[i4] + 64, &As_[1][(i4 * 512 + tid) * 8]);
#pragma unroll
  for (int i2 = 0; i2 < 2; i2++) gld16(Bt + bOff[i2] + 64, &Bs_[1][(i2 * 512 + tid) * 8]);
  asm volatile("s_waitcnt vmcnt(6)" ::: "memory");
  __builtin_amdgcn_s_barrier();

  const int KT = K >> 6;
  int cur = 0;
  for (int t = 0; t < KT; ++t) {
    const u16* as = As_[cur];
    const u16* bs = Bs_[cur];
    const int stg = (cur == 0) ? 2 : cur - 1;  // (t+2)%3
    const bool more = (t + 2) < KT;
    const size_t k2 = (size_t)(t + 2) * 64;

    bf16x8 af0[4], bf0[4], af1[4], bf1[4];
#pragma unroll
    for (int mt = 0; mt < 4; mt++) {
      af0[mt] = *(const bf16x8*)&as[(wrow + mt * 16 + r) * 64 + ko0];
      af1[mt] = *(const bf16x8*)&as[(wrow + mt * 16 + r) * 64 + ko1];
    }
#pragma unroll
    for (int nt = 0; nt < 4; nt++) {
      bf0[nt] = *(const bf16x8*)&bs[(wcol + nt * 16 + r) * 64 + ko0];
      bf1[nt] = *(const bf16x8*)&bs[(wcol + nt * 16 + r) * 64 + ko1];
    }

    if (more) {
#pragma unroll
      for (int i4 = 0; i4 < 4; i4++)
        gld16(A + aOff[i4] + k2, &As_[stg][(i4 * 512 + tid) * 8]);
#pragma unroll
      for (int i2 = 0; i2 < 2; i2++)
        gld16(Bt + bOff[i2] + k2, &Bs_[stg][(i2 * 512 + tid) * 8]);
    }

#pragma unroll
    for (int mt = 0; mt < 4; mt++)
#pragma unroll
      for (int nt = 0; nt < 4; nt++)
        acc[mt][nt] = MFMA(af0[mt], bf0[nt], acc[mt][nt]);
#pragma unroll
    for (int mt = 0; mt < 4; mt++)
#pragma unroll
      for (int nt = 0; nt < 4; nt++)
        acc[mt][nt] = MFMA(af1[mt], bf1[nt], acc[mt][nt]);

    if (t + 1 < KT) {
      if (more) asm volatile("s_waitcnt vmcnt(6)" ::: "memory");
      else      asm volatile("s_waitcnt vmcnt(0)" ::: "memory");
    }
    __builtin_amdgcn_s_barrier();
    cur = (cur == 2) ? 0 : cur + 1;
  }

  // epilogue: C[row][col], col = r (+16*nt), row = g*4 + q (+16*mt)
#pragma unroll
  for (int mt = 0; mt < 4; mt++) {
#pragma unroll
    for (int nt = 0; nt < 4; nt++) {
      int col = bn * 128 + wcol + nt * 16 + r;
      float bv;
      if (MODE == 4) {
        int sec = col >> 10, hcol = col & 1023;  // sec is block-uniform
        bv = (sec == 0) ? b0[hcol] : (sec == 1) ? b1[hcol] : b2[hcol];
      } else {
        bv = b0[col];
      }
#pragma unroll
      for (int q = 0; q < 4; q++) {
        int row = bm * 256 + wrow + mt * 16 + g * 4 + q;
        float v = acc[mt][nt][q] + bv;
        if (MODE == 3) {
          ((float*)outp)[(size_t)row * N + col] = v + resid[(size_t)row * N + col];
        } else if (MODE == 4) {
          int sec = col >> 10, hcol = col & 1023;
          int head = hcol >> 6, hd = hcol & 63;
          int bb = row >> 11, tt = row & 2047;
          size_t hbase = ((size_t)bb * 16 + head) * 131072;
          u16* qout = (u16*)outp;
          if (sec == 0) {
            qout[hbase + qk_off(tt, hd)] = f2b(v * scale);
          } else if (sec == 1) {
            (qout + 8388608)[hbase + qk_off(tt, hd)] = f2b(v);
          } else {
            (qout + 16777216)[hbase + v_off(tt, hd)] = f2b(v);
          }
        }
      }
    }
  }
}

// ---------------------------------------------------------------------------
// Flash attention v4 (unchanged). Causal, Q pre-scaled by log2e/32.
__global__ __launch_bounds__(256) void attn_kernel(
    const u16* __restrict__ Q, const u16* __restrict__ Kc,
    const u16* __restrict__ Vt, const float* __restrict__ x,
    float* __restrict__ x1, u16* __restrict__ xb1) {
  const int bh = blockIdx.x & 63;
  const int slot = blockIdx.x >> 6;
  const int tid = threadIdx.x;
  const int wid = tid >> 6, lane = tid & 63;
  const int g = lane >> 4, c = lane & 15;
  const u16* Qh = Q + (size_t)bh * 131072;
  const u16* Kh = Kc + (size_t)bh * 131072;
  const u16* Vh = Vt + (size_t)bh * 131072;
  const int b = bh >> 4, head = bh & 15;

  __shared__ __attribute__((aligned(16))) u16 Ks[8192];
  __shared__ __attribute__((aligned(16))) u16 Vs[8192];
  __shared__ __attribute__((aligned(16))) u16 P[4][32][72];

  bf16x8 ones;
#pragma unroll
  for (int i = 0; i < 8; i++) ones[i] = (__bf16)1.0f;

  const f32x4 zero4 = {0.f, 0.f, 0.f, 0.f};

  for (int phase = 0; phase < 2; ++phase) {
    const int bt = phase ? (15 - slot) : slot;
    const int q0b = bt * 128;
    const int q0 = q0b + wid * 32;
    const int kendw = q0 + 32;
    const int nkt = bt + 1;

    bf16x8 qf[2][2];
#pragma unroll
    for (int mt = 0; mt < 2; mt++)
#pragma unroll
      for (int h = 0; h < 2; h++)
        qf[mt][h] = *(const bf16x8*)&Qh[(((q0 >> 4) + mt) * 2 + h) * 512 + lane * 8];

    f32x4 o[2][4];
    f32x4 lac[2];
#pragma unroll
    for (int mt = 0; mt < 2; mt++) {
      lac[mt] = zero4;
#pragma unroll
      for (int i = 0; i < 4; i++) o[mt][i] = zero4;
    }

    for (int kt = 0; kt < nkt; ++kt) {
      const int k0 = kt * 128;
#pragma unroll
      for (int r2 = 0; r2 < 4; r2++) {
        int idx = (r2 * 256 + tid) * 8;
        gld16(Kh + (size_t)k0 * 64 + idx, Ks + idx);
        gld16(Vh + (size_t)k0 * 64 + idx, Vs + idx);
      }
      __syncthreads();

#pragma unroll
      for (int s2 = 0; s2 < 2; ++s2) {
        const int k0s = k0 + s2 * 64;
        if (k0s < kendw) {
          bf16x8 kf[4][2], vf[4][2];
#pragma unroll
          for (int nt = 0; nt < 4; nt++)
#pragma unroll
            for (int h = 0; h < 2; h++) {
              kf[nt][h] = *(const bf16x8*)&Ks[s2 * 4096 + (nt * 2 + h) * 512 + lane * 8];
              vf[nt][h] = *(const bf16x8*)&Vs[s2 * 4096 + (nt * 2 + h) * 512 + lane * 8];
            }

          f32x4 sv[2][4];
#pragma unroll
          for (int mt = 0; mt < 2; mt++)
#pragma unroll
            for (int nt = 0; nt < 4; nt++) sv[mt][nt] = zero4;
#pragma unroll
          for (int nt = 0; nt < 4; nt++)
#pragma unroll
            for (int mt = 0; mt < 2; mt++) {
              sv[mt][nt] = MFMA(qf[mt][0], kf[nt][0], sv[mt][nt]);
              sv[mt][nt] = MFMA(qf[mt][1], kf[nt][1], sv[mt][nt]);
            }

          if (k0s + 64 > q0) {
#pragma unroll
            for (int mt = 0; mt < 2; mt++)
#pragma unroll
              for (int rr = 0; rr < 4; rr++) {
                int q = q0 + mt * 16 + g * 4 + rr;
#pragma unroll
                for (int nt = 0; nt < 4; nt++)
                  if (k0s + nt * 16 + c > q) sv[mt][nt][rr] = -1e30f;
              }
          }

#pragma unroll
          for (int mt = 0; mt < 2; mt++)
#pragma unroll
            for (int rr = 0; rr < 4; rr++) {
              union { u16x4 u; bf16x4 h; } pw;
#pragma unroll
              for (int nt = 0; nt < 4; nt++)
                pw.h[nt] = (__bf16)__builtin_amdgcn_exp2f(sv[mt][nt][rr]);
              *(u16x4*)&P[wid][mt * 16 + g * 4 + rr][4 * c] = pw.u;
            }

          asm volatile("s_waitcnt lgkmcnt(0)" ::: "memory");

#pragma unroll
          for (int mt = 0; mt < 2; mt++) {
            bf16x8 pf0 = *(const bf16x8*)&P[wid][mt * 16 + c][g * 8];
            bf16x8 pf1 = *(const bf16x8*)&P[wid][mt * 16 + c][32 + g * 8];
            lac[mt] = MFMA(pf0, ones, lac[mt]);
            lac[mt] = MFMA(pf1, ones, lac[mt]);
#pragma unroll
            for (int ot = 0; ot < 4; ot++) {
              f32x4 oo = MFMA(pf0, vf[ot][0], o[mt][ot]);
              o[mt][ot] = MFMA(pf1, vf[ot][1], oo);
            }
          }
        }
      }
      __syncthreads();
    }

    float inv[2][4];
#pragma unroll
    for (int mt = 0; mt < 2; mt++)
#pragma unroll
      for (int rr = 0; rr < 4; rr++) inv[mt][rr] = 1.0f / lac[mt][rr];
#pragma unroll
    for (int mt = 0; mt < 2; mt++)
#pragma unroll
      for (int ot = 0; ot < 4; ot++)
#pragma unroll
        for (int rr = 0; rr < 4; rr++) {
          int t = q0 + mt * 16 + g * 4 + rr;
          int hd = ot * 16 + c;
          size_t xi = ((size_t)b * 2048 + t) * 1024 + head * 64 + hd;
          float v = x[xi] + o[mt][ot][rr] * inv[mt][rr];
          x1[xi] = v;
          xb1[xi] = f2b(v);
        }
  }
}

// ---------------------------------------------------------------------------
extern "C" void kernel_launch(void* const* d_in, const int* in_sizes, int n_in,
                              void* d_out, int out_size, void* d_ws, size_t ws_size,
                              hipStream_t stream) {
  (void)in_sizes; (void)n_in; (void)out_size; (void)ws_size;
  const float* x = (const float*)d_in[0];
  const float* Wq = (const float*)d_in[1];
  const float* bq = (const float*)d_in[2];
  const float* Wk = (const float*)d_in[3];
  const float* bk = (const float*)d_in[4];
  const float* Wv = (const float*)d_in[5];
  const float* bv = (const float*)d_in[6];
  const float* W1 = (const float*)d_in[7];
  const float* b1 = (const float*)d_in[8];
  const float* W2 = (const float*)d_in[9];
  const float* b2 = (const float*)d_in[10];

  char* ws = (char*)d_ws;
  size_t off = 0;
  auto alloc = [&](size_t bytes) {
    char* p = ws + off;
    off += (bytes + 255) & ~(size_t)255;
    return p;
  };
  u16* xb    = (u16*)alloc(8192ull * 1024 * 2);   // bf16(x)
  u16* Wqkvt = (u16*)alloc(3072ull * 1024 * 2);   // [3072][1024] bf16 (Wq|Wk|Wv rows)
  u16* W1t   = (u16*)alloc(4096ull * 1024 * 2);
  u16* W2t   = (u16*)alloc(1024ull * 4096 * 2);
  u16* Qb    = (u16*)alloc(3ull * 8192 * 1024 * 2);  // Q|K|V frag-ordered, contiguous
  float* x1  = (float*)alloc(8192ull * 1024 * 4); // x + attn (fp32 residual)
  u16* hb    = (u16*)alloc(8192ull * 4096 * 2);   // gelu(x1@W1+b1)
  u16* xb1   = xb;  // xb dead after QKV gemm; reuse for bf16(x1)
  u16* Kb    = Qb + 8388608;
  u16* Vtb   = Qb + 16777216;

  const float qscale = 1.4426950408889634f / 32.0f;  // log2e / sqrt(H)

  // 1. prep: x -> bf16 + all weight transposes, ONE launch (8192 + 11264 blocks)
  prep<<<dim3(19456), dim3(32, 8), 0, stream>>>(
      x, xb, Wq, Wk, Wv, W1, W2, Wqkvt, W1t, W2t);
  // 2. fused QKV projection (M=8192, N=3072, K=1024) -> frag-ordered Q/K/V
  //    256x128 3-buffer (768 blocks = 3 exact rounds; scatter fits registers)
  gemm256<4><<<dim3(768), dim3(512), 0, stream>>>(
      xb, Wqkvt, bq, bk, bv, Qb, nullptr, 3072, 1024, qscale);
  // 3. attention + residual 1  (512 blocks; paired 128-row tiles)
  attn_kernel<<<dim3(512), dim3(256), 0, stream>>>(Qb, Kb, Vtb, x, x1, xb1);
  // 4. MLP1: gelu(x1 @ W1 + b1): 256x256 8-phase counted, PERSISTENT 2 bn/block
  //    (256 blocks = 1 round; rep-1 fill hides under rep-0 epilogue)
  gemm8p<2><<<dim3(256), dim3(512), 0, stream>>>(
      xb1, W1t, b1, hb, 4096, 1024);
  // 5. MLP2 + residual 2 -> d_out (fp32) (M=8192, N=1024, K=4096): 32 x 8 = 256
  //    blocks = exactly 1 block/CU, one clean round, 64 K-tiles of pipeline.
  gemm256<3><<<dim3(256), dim3(512), 0, stream>>>(
      hb, W2t, b2, nullptr, nullptr, d_out, x1, 1024, 4096, 1.0f);
}

// Round 9
// 435.362 us; speedup vs baseline: 1.0345x; 1.0345x over previous
//
#include <hip/hip_runtime.h>
#include <cstdint>
#include <cstddef>

// Problem constants: B=4, T=2048, H=1024, NH=16, HD=64, FF=4096, M=B*T=8192
typedef unsigned short u16;
typedef __attribute__((ext_vector_type(8))) __bf16 bf16x8;
typedef __attribute__((ext_vector_type(4))) __bf16 bf16x4;
typedef __attribute__((ext_vector_type(4))) float f32x4;
typedef __attribute__((ext_vector_type(4))) u16 u16x4;

#define MFMA(a, b, c) __builtin_amdgcn_mfma_f32_16x16x32_bf16((a), (b), (c), 0, 0, 0)

__device__ __forceinline__ u16 f2b(float f) {  // native RNE cvt (1-2 ops)
  union { __bf16 h; u16 u; } v;
  v.h = (__bf16)f;
  return v.u;
}

__device__ __forceinline__ void gld16(const void* g, void* l) {
  __builtin_amdgcn_global_load_lds(
      (__attribute__((address_space(1))) void*)(void*)(g),
      (__attribute__((address_space(3))) void*)(l), 16, 0, 0);
}

// Fragment-ordered layouts (per head, 131072 u16 = 2048x64):
__device__ __forceinline__ size_t qk_off(int t, int hd) {
  return (size_t)((((t >> 4) * 2 + (hd >> 5)) * 512)
                  + ((((hd >> 3) & 3) * 16 + (t & 15)) * 8) + (hd & 7));
}
__device__ __forceinline__ size_t v_off(int t, int hd) {
  int kk = ((t & 15) << 2) | ((t >> 4) & 3);
  return (size_t)(((t >> 6) * 4096)
                  + (((hd >> 4) * 2 + (kk >> 5)) * 512)
                  + ((((kk >> 3) & 3) * 16 + (hd & 15)) * 8) + (kk & 7));
}

// ---------------------------------------------------------------------------
// prep: xconv (fp32->bf16) + all weight transposes in ONE launch.
__global__ void prep(const float* __restrict__ x, u16* __restrict__ xb,
                     const float* __restrict__ Wq, const float* __restrict__ Wk,
                     const float* __restrict__ Wv, const float* __restrict__ W1,
                     const float* __restrict__ W2, u16* __restrict__ Wqkvt,
                     u16* __restrict__ W1t, u16* __restrict__ W2t) {
  int blk = blockIdx.x;
  int tx = threadIdx.x, ty = threadIdx.y;
  if (blk < 8192) {
    int i = (blk * 256 + ty * 32 + tx) * 4;
    float4 v = *(const float4*)(x + i);
    u16x4 o;
    o[0] = f2b(v.x); o[1] = f2b(v.y); o[2] = f2b(v.z); o[3] = f2b(v.w);
    *(u16x4*)(xb + i) = o;
    return;
  }
  blk -= 8192;
  __shared__ float tile[32][33];
  const float* W;
  u16* Wt;
  int Kd, Nd, nx;
  if (blk < 3072) {
    int s = blk >> 10;
    blk &= 1023;
    W = (s == 0) ? Wq : (s == 1) ? Wk : Wv;
    Wt = Wqkvt + (size_t)s * 1048576;
    Kd = 1024; Nd = 1024; nx = 32;
  } else if (blk < 7168) {
    blk -= 3072; W = W1; Wt = W1t; Kd = 1024; Nd = 4096; nx = 128;
  } else {
    blk -= 7168; W = W2; Wt = W2t; Kd = 4096; Nd = 1024; nx = 32;
  }
  int n0 = (blk % nx) * 32, k0 = (blk / nx) * 32;
#pragma unroll
  for (int i = 0; i < 4; i++)
    tile[ty + i * 8][tx] = W[(size_t)(k0 + ty + i * 8) * Nd + n0 + tx];
  __syncthreads();
#pragma unroll
  for (int i = 0; i < 4; i++)
    Wt[(size_t)(n0 + ty + i * 8) * Kd + k0 + tx] = f2b(tile[tx][ty + i * 8]);
}

// ---------------------------------------------------------------------------
// 256x256 8-phase COUNTED-vmcnt GEMM (R7 winner, NON-persistent — R8's
// persistent rep loop spilled: VGPR 128, +32MB scratch WRITE). BK=64, 8
// waves; quadrant (mh,nh) selects the operand half; gray-coded phase order
// (0,0),(0,1),(1,1),(1,0) frees A0 after ph1, B1 after ph2. Staging:
// ph0 A1(t+1), ph1 B0(t+1), ph2 A0(t+2)->buf[t], ph3 B1(t+2)->buf[t].
// End-of-tile vmcnt(4): only A0/B1(t+2) in flight; never drains mid-loop.
// XCD map: xcd owns bm in [4xcd,4xcd+4), bn chunks of 4. MODE 2: gelu out.
template <int MODE>
__global__ __launch_bounds__(512, 2) void gemm8p(
    const u16* __restrict__ A, const u16* __restrict__ Bt,
    const float* __restrict__ b0, void* __restrict__ outp,
    int N, int K) {
  __shared__ __attribute__((aligned(16))) u16 As_[2][16384];
  __shared__ __attribute__((aligned(16))) u16 Bs_[2][16384];
  const int tid = threadIdx.x;
  const int wid = tid >> 6, lane = tid & 63;
  const int g = lane >> 4, r = lane & 15;

  const int xcd = blockIdx.x & 7;
  const int ii = blockIdx.x >> 3;
  const int c4 = ii >> 4, w = ii & 15;
  const int bm = xcd * 4 + (w >> 2);
  const int bn = c4 * 4 + (w & 3);

  const int mrow = (wid >> 2) * 64;   // wave's 64-row band within each A-half
  const int ncol = (wid & 3) * 32;    // wave's 32-col band within each B-half

  const int ko0 = ((0 * 4 + g) ^ (r & 7)) * 8;
  const int ko1 = ((1 * 4 + g) ^ (r & 7)) * 8;

  size_t aOff[4], bOff[4];
#pragma unroll
  for (int i4 = 0; i4 < 4; i4++) {
    int cc = i4 * 512 + tid, row = cc >> 3;
    int js = ((cc & 7) ^ (row & 7)) * 8;
    aOff[i4] = (size_t)(bm * 256 + row) * K + js;
    bOff[i4] = (size_t)(bn * 256 + row) * K + js;
  }

  f32x4 acc[8][4];
  const f32x4 zero4 = {0.f, 0.f, 0.f, 0.f};
#pragma unroll
  for (int i = 0; i < 8; i++)
#pragma unroll
    for (int j = 0; j < 4; j++) acc[i][j] = zero4;

  // prologue: all 4 units of tile 0 -> buf0; A0(1), B1(1) -> buf1
#pragma unroll
  for (int i4 = 0; i4 < 4; i4++) {
    gld16(A + aOff[i4], &As_[0][(i4 * 512 + tid) * 8]);
    gld16(Bt + bOff[i4], &Bs_[0][(i4 * 512 + tid) * 8]);
  }
  gld16(A + aOff[0] + 64, &As_[1][(0 * 512 + tid) * 8]);
  gld16(A + aOff[1] + 64, &As_[1][(1 * 512 + tid) * 8]);
  gld16(Bt + bOff[2] + 64, &Bs_[1][(2 * 512 + tid) * 8]);
  gld16(Bt + bOff[3] + 64, &Bs_[1][(3 * 512 + tid) * 8]);
  asm volatile("s_waitcnt vmcnt(4)" ::: "memory");  // tile 0 landed
  __builtin_amdgcn_s_barrier();

  const int KT = K >> 6;
  for (int t = 0; t < KT; ++t) {
    const int p = t & 1, pn = p ^ 1;
    const u16* as = As_[p];
    const u16* bs = Bs_[p];
    const bool m1 = (t + 1) < KT, m2 = (t + 2) < KT;
    const size_t k1 = (size_t)(t + 1) * 64, k2 = (size_t)(t + 2) * 64;
    bf16x8 af[4][2], bf[2][2];

    // ---- phase 0: (mh0, nh0); stage A1(t+1) ----
#pragma unroll
    for (int mt = 0; mt < 4; mt++) {
      int rw = mrow + mt * 16 + r;
      af[mt][0] = *(const bf16x8*)&as[rw * 64 + ko0];
      af[mt][1] = *(const bf16x8*)&as[rw * 64 + ko1];
    }
#pragma unroll
    for (int nt = 0; nt < 2; nt++) {
      int rw = ncol + nt * 16 + r;
      bf[nt][0] = *(const bf16x8*)&bs[rw * 64 + ko0];
      bf[nt][1] = *(const bf16x8*)&bs[rw * 64 + ko1];
    }
    if (m1) {
      gld16(A + aOff[2] + k1, &As_[pn][(1024 + tid) * 8]);
      gld16(A + aOff[3] + k1, &As_[pn][(1536 + tid) * 8]);
    }
    __builtin_amdgcn_s_barrier();
    asm volatile("s_waitcnt lgkmcnt(0)" ::: "memory");
    __builtin_amdgcn_sched_barrier(0);
    __builtin_amdgcn_s_setprio(1);
#pragma unroll
    for (int mt = 0; mt < 4; mt++)
#pragma unroll
      for (int nt = 0; nt < 2; nt++)
        acc[mt][nt] = MFMA(af[mt][1], bf[nt][1], MFMA(af[mt][0], bf[nt][0], acc[mt][nt]));
    __builtin_amdgcn_s_setprio(0);
    __builtin_amdgcn_s_barrier();

    // ---- phase 1: (mh0, nh1); stage B0(t+1) ----
#pragma unroll
    for (int nt = 0; nt < 2; nt++) {
      int rw = 128 + ncol + nt * 16 + r;
      bf[nt][0] = *(const bf16x8*)&bs[rw * 64 + ko0];
      bf[nt][1] = *(const bf16x8*)&bs[rw * 64 + ko1];
    }
    if (m1) {
      gld16(Bt + bOff[0] + k1, &Bs_[pn][(tid) * 8]);
      gld16(Bt + bOff[1] + k1, &Bs_[pn][(512 + tid) * 8]);
    }
    __builtin_amdgcn_s_barrier();
    asm volatile("s_waitcnt lgkmcnt(0)" ::: "memory");
    __builtin_amdgcn_sched_barrier(0);
    __builtin_amdgcn_s_setprio(1);
#pragma unroll
    for (int mt = 0; mt < 4; mt++)
#pragma unroll
      for (int nt = 0; nt < 2; nt++)
        acc[mt][2 + nt] = MFMA(af[mt][1], bf[nt][1], MFMA(af[mt][0], bf[nt][0], acc[mt][2 + nt]));
    __builtin_amdgcn_s_setprio(0);
    __builtin_amdgcn_s_barrier();   // A0 region of buf[p] now free

    // ---- phase 2: (mh1, nh1); stage A0(t+2) into buf[p] ----
#pragma unroll
    for (int mt = 0; mt < 4; mt++) {
      int rw = 128 + mrow + mt * 16 + r;
      af[mt][0] = *(const bf16x8*)&as[rw * 64 + ko0];
      af[mt][1] = *(const bf16x8*)&as[rw * 64 + ko1];
    }
    if (m2) {
      gld16(A + aOff[0] + k2, &As_[p][(tid) * 8]);
      gld16(A + aOff[1] + k2, &As_[p][(512 + tid) * 8]);
    }
    __builtin_amdgcn_s_barrier();
    asm volatile("s_waitcnt lgkmcnt(0)" ::: "memory");
    __builtin_amdgcn_sched_barrier(0);
    __builtin_amdgcn_s_setprio(1);
#pragma unroll
    for (int mt = 0; mt < 4; mt++)
#pragma unroll
      for (int nt = 0; nt < 2; nt++)
        acc[4 + mt][2 + nt] = MFMA(af[mt][1], bf[nt][1], MFMA(af[mt][0], bf[nt][0], acc[4 + mt][2 + nt]));
    __builtin_amdgcn_s_setprio(0);
    __builtin_amdgcn_s_barrier();   // B1 region of buf[p] now free

    // ---- phase 3: (mh1, nh0); stage B1(t+2) into buf[p] ----
#pragma unroll
    for (int nt = 0; nt < 2; nt++) {
      int rw = ncol + nt * 16 + r;
      bf[nt][0] = *(const bf16x8*)&bs[rw * 64 + ko0];
      bf[nt][1] = *(const bf16x8*)&bs[rw * 64 + ko1];
    }
    if (m2) {
      gld16(Bt + bOff[2] + k2, &Bs_[p][(1024 + tid) * 8]);
      gld16(Bt + bOff[3] + k2, &Bs_[p][(1536 + tid) * 8]);
    }
    __builtin_amdgcn_s_barrier();
    asm volatile("s_waitcnt lgkmcnt(0)" ::: "memory");
    __builtin_amdgcn_sched_barrier(0);
    __builtin_amdgcn_s_setprio(1);
#pragma unroll
    for (int mt = 0; mt < 4; mt++)
#pragma unroll
      for (int nt = 0; nt < 2; nt++)
        acc[4 + mt][nt] = MFMA(af[mt][1], bf[nt][1], MFMA(af[mt][0], bf[nt][0], acc[4 + mt][nt]));
    __builtin_amdgcn_s_setprio(0);
    if (m2) asm volatile("s_waitcnt vmcnt(4)" ::: "memory");
    else    asm volatile("s_waitcnt vmcnt(0)" ::: "memory");
    __builtin_amdgcn_s_barrier();
  }

  // epilogue
#pragma unroll
  for (int am = 0; am < 8; am++) {
#pragma unroll
    for (int an = 0; an < 4; an++) {
      int col = bn * 256 + (an >> 1) * 128 + ncol + (an & 1) * 16 + r;
      float bv = b0[col];
#pragma unroll
      for (int q = 0; q < 4; q++) {
        int row = bm * 256 + (am >> 2) * 128 + mrow + (am & 3) * 16 + g * 4 + q;
        float v = acc[am][an][q] + bv;
        if (MODE == 2) {
          const float c1 = -2.3025850929940457f;
          const float c2 = c1 * 0.044715f;
          float t2 = v * v;
          float z = v * (c1 + c2 * t2);
          float sg = 1.0f / (1.0f + __builtin_amdgcn_exp2f(z));
          ((u16*)outp)[(size_t)row * N + col] = f2b(v * sg);
        }
      }
    }
  }
}

// ---------------------------------------------------------------------------
// 256x128 3-buffer counted-vmcnt GEMM, barrier-light K-loop (R3 winner).
// acc[4][4] = 64 AGPRs: register headroom for the MODE-4 scatter epilogue.
// MODE 3: fp32 out = v + resid   MODE 4: fused QKV scatter (frag-order)
template <int MODE>
__global__ __launch_bounds__(512, 2) void gemm256(
    const u16* __restrict__ A, const u16* __restrict__ Bt,
    const float* __restrict__ b0, const float* __restrict__ b1,
    const float* __restrict__ b2, void* __restrict__ outp,
    const float* __restrict__ resid, int N, int K, float scale) {
  __shared__ __attribute__((aligned(16))) u16 As_[3][16384];
  __shared__ __attribute__((aligned(16))) u16 Bs_[3][8192];
  const int tid = threadIdx.x;
  const int wid = tid >> 6, lane = tid & 63;
  const int g = lane >> 4, r = lane & 15;

  const int xcd = blockIdx.x & 7;
  const int ii = blockIdx.x >> 3;
  const int bm = xcd * 4 + ((ii & 31) >> 3);
  const int bn = (ii >> 5) * 8 + (ii & 7);

  const int wrow = (wid >> 1) * 64;   // 4 M-waves
  const int wcol = (wid & 1) * 64;    // 2 N-waves

  const int ko0 = ((0 * 4 + g) ^ (r & 7)) * 8;
  const int ko1 = ((1 * 4 + g) ^ (r & 7)) * 8;

  size_t aOff[4], bOff[2];
#pragma unroll
  for (int i4 = 0; i4 < 4; i4++) {
    int cc = i4 * 512 + tid, row = cc >> 3;
    int js = ((cc & 7) ^ (row & 7)) * 8;
    aOff[i4] = (size_t)(bm * 256 + row) * K + js;
  }
#pragma unroll
  for (int i2 = 0; i2 < 2; i2++) {
    int cc = i2 * 512 + tid, row = cc >> 3;
    int js = ((cc & 7) ^ (row & 7)) * 8;
    bOff[i2] = (size_t)(bn * 128 + row) * K + js;
  }

  f32x4 acc[4][4];
  const f32x4 zero4 = {0.f, 0.f, 0.f, 0.f};
#pragma unroll
  for (int i = 0; i < 4; i++)
#pragma unroll
    for (int j = 0; j < 4; j++) acc[i][j] = zero4;

  // prologue: stage tiles 0 and 1; wait for tile 0 only (tile 1 in flight)
#pragma unroll
  for (int i4 = 0; i4 < 4; i4++) gld16(A + aOff[i4], &As_[0][(i4 * 512 + tid) * 8]);
#pragma unroll
  for (int i2 = 0; i2 < 2; i2++) gld16(Bt + bOff[i2], &Bs_[0][(i2 * 512 + tid) * 8]);
#pragma unroll
  for (int i4 = 0; i4 < 4; i4++) gld16(A + aOff[i4] + 64, &As_[1][(i4 * 512 + tid) * 8]);
#pragma unroll
  for (int i2 = 0; i2 < 2; i2++) gld16(Bt + bOff[i2] + 64, &Bs_[1][(i2 * 512 + tid) * 8]);
  asm volatile("s_waitcnt vmcnt(6)" ::: "memory");
  __builtin_amdgcn_s_barrier();

  const int KT = K >> 6;
  int cur = 0;
  for (int t = 0; t < KT; ++t) {
    const u16* as = As_[cur];
    const u16* bs = Bs_[cur];
    const int stg = (cur == 0) ? 2 : cur - 1;  // (t+2)%3
    const bool more = (t + 2) < KT;
    const size_t k2 = (size_t)(t + 2) * 64;

    bf16x8 af0[4], bf0[4], af1[4], bf1[4];
#pragma unroll
    for (int mt = 0; mt < 4; mt++) {
      af0[mt] = *(const bf16x8*)&as[(wrow + mt * 16 + r) * 64 + ko0];
      af1[mt] = *(const bf16x8*)&as[(wrow + mt * 16 + r) * 64 + ko1];
    }
#pragma unroll
    for (int nt = 0; nt < 4; nt++) {
      bf0[nt] = *(const bf16x8*)&bs[(wcol + nt * 16 + r) * 64 + ko0];
      bf1[nt] = *(const bf16x8*)&bs[(wcol + nt * 16 + r) * 64 + ko1];
    }

    if (more) {
#pragma unroll
      for (int i4 = 0; i4 < 4; i4++)
        gld16(A + aOff[i4] + k2, &As_[stg][(i4 * 512 + tid) * 8]);
#pragma unroll
      for (int i2 = 0; i2 < 2; i2++)
        gld16(Bt + bOff[i2] + k2, &Bs_[stg][(i2 * 512 + tid) * 8]);
    }

#pragma unroll
    for (int mt = 0; mt < 4; mt++)
#pragma unroll
      for (int nt = 0; nt < 4; nt++)
        acc[mt][nt] = MFMA(af0[mt], bf0[nt], acc[mt][nt]);
#pragma unroll
    for (int mt = 0; mt < 4; mt++)
#pragma unroll
      for (int nt = 0; nt < 4; nt++)
        acc[mt][nt] = MFMA(af1[mt], bf1[nt], acc[mt][nt]);

    if (t + 1 < KT) {
      if (more) asm volatile("s_waitcnt vmcnt(6)" ::: "memory");
      else      asm volatile("s_waitcnt vmcnt(0)" ::: "memory");
    }
    __builtin_amdgcn_s_barrier();
    cur = (cur == 2) ? 0 : cur + 1;
  }

  // epilogue: C[row][col], col = r (+16*nt), row = g*4 + q (+16*mt)
#pragma unroll
  for (int mt = 0; mt < 4; mt++) {
#pragma unroll
    for (int nt = 0; nt < 4; nt++) {
      int col = bn * 128 + wcol + nt * 16 + r;
      float bv;
      if (MODE == 4) {
        int sec = col >> 10, hcol = col & 1023;  // sec is block-uniform
        bv = (sec == 0) ? b0[hcol] : (sec == 1) ? b1[hcol] : b2[hcol];
      } else {
        bv = b0[col];
      }
#pragma unroll
      for (int q = 0; q < 4; q++) {
        int row = bm * 256 + wrow + mt * 16 + g * 4 + q;
        float v = acc[mt][nt][q] + bv;
        if (MODE == 3) {
          ((float*)outp)[(size_t)row * N + col] = v + resid[(size_t)row * N + col];
        } else if (MODE == 4) {
          int sec = col >> 10, hcol = col & 1023;
          int head = hcol >> 6, hd = hcol & 63;
          int bb = row >> 11, tt = row & 2047;
          size_t hbase = ((size_t)bb * 16 + head) * 131072;
          u16* qout = (u16*)outp;
          if (sec == 0) {
            qout[hbase + qk_off(tt, hd)] = f2b(v * scale);
          } else if (sec == 1) {
            (qout + 8388608)[hbase + qk_off(tt, hd)] = f2b(v);
          } else {
            (qout + 16777216)[hbase + v_off(tt, hd)] = f2b(v);
          }
        }
      }
    }
  }
}

// ---------------------------------------------------------------------------
// Flash attention v5: K/V staging for tile kt+1 is issued MID-TILE (after a
// barrier guaranteeing all waves' Ks/Vs reads are done) and its latency
// hides under s2=1's register-held compute (QK+softmax+PV ~800+ cyc >> L2
// latency; K/V is XCD-L2-resident: all 8 slot-blocks of head bh map to XCD
// bh%8 since 8|64). Same LDS, same 2 barriers/tile as v4 — only the staging
// position moved. Causal, Q pre-scaled by log2e/32.
__global__ __launch_bounds__(256) void attn_kernel(
    const u16* __restrict__ Q, const u16* __restrict__ Kc,
    const u16* __restrict__ Vt, const float* __restrict__ x,
    float* __restrict__ x1, u16* __restrict__ xb1) {
  const int bh = blockIdx.x & 63;
  const int slot = blockIdx.x >> 6;
  const int tid = threadIdx.x;
  const int wid = tid >> 6, lane = tid & 63;
  const int g = lane >> 4, c = lane & 15;
  const u16* Qh = Q + (size_t)bh * 131072;
  const u16* Kh = Kc + (size_t)bh * 131072;
  const u16* Vh = Vt + (size_t)bh * 131072;
  const int b = bh >> 4, head = bh & 15;

  __shared__ __attribute__((aligned(16))) u16 Ks[8192];
  __shared__ __attribute__((aligned(16))) u16 Vs[8192];
  __shared__ __attribute__((aligned(16))) u16 P[4][32][72];

  bf16x8 ones;
#pragma unroll
  for (int i = 0; i < 8; i++) ones[i] = (__bf16)1.0f;

  const f32x4 zero4 = {0.f, 0.f, 0.f, 0.f};

  for (int phase = 0; phase < 2; ++phase) {
    const int bt = phase ? (15 - slot) : slot;
    const int q0 = bt * 128 + wid * 32;
    const int kendw = q0 + 32;
    const int nkt = bt + 1;

    bf16x8 qf[2][2];
#pragma unroll
    for (int mt = 0; mt < 2; mt++)
#pragma unroll
      for (int h = 0; h < 2; h++)
        qf[mt][h] = *(const bf16x8*)&Qh[(((q0 >> 4) + mt) * 2 + h) * 512 + lane * 8];

    f32x4 o[2][4];
    f32x4 lac[2];
#pragma unroll
    for (int mt = 0; mt < 2; mt++) {
      lac[mt] = zero4;
#pragma unroll
      for (int i = 0; i < 4; i++) o[mt][i] = zero4;
    }

    // prologue: stage K/V tile 0 (safe: all waves passed the previous
    // phase's last mid-tile barrier, so no outstanding Ks/Vs reads)
#pragma unroll
    for (int r2 = 0; r2 < 4; r2++) {
      int idx = (r2 * 256 + tid) * 8;
      gld16(Kh + idx, Ks + idx);
      gld16(Vh + idx, Vs + idx);
    }

    for (int kt = 0; kt < nkt; ++kt) {
      const int k0 = kt * 128;
      __syncthreads();  // staging landed (compiler drains vmcnt before barrier)

      // ---- s2 = 0: full chain (k0 <= bt*128 <= q0 < kendw: always live) ----
      {
        bf16x8 kf[4][2], vf[4][2];
#pragma unroll
        for (int nt = 0; nt < 4; nt++)
#pragma unroll
          for (int h = 0; h < 2; h++) {
            kf[nt][h] = *(const bf16x8*)&Ks[(nt * 2 + h) * 512 + lane * 8];
            vf[nt][h] = *(const bf16x8*)&Vs[(nt * 2 + h) * 512 + lane * 8];
          }

        f32x4 sv[2][4];
#pragma unroll
        for (int mt = 0; mt < 2; mt++)
#pragma unroll
          for (int nt = 0; nt < 4; nt++) sv[mt][nt] = zero4;
#pragma unroll
        for (int nt = 0; nt < 4; nt++)
#pragma unroll
          for (int mt = 0; mt < 2; mt++) {
            sv[mt][nt] = MFMA(qf[mt][0], kf[nt][0], sv[mt][nt]);
            sv[mt][nt] = MFMA(qf[mt][1], kf[nt][1], sv[mt][nt]);
          }

        if (k0 + 64 > q0) {
#pragma unroll
          for (int mt = 0; mt < 2; mt++)
#pragma unroll
            for (int rr = 0; rr < 4; rr++) {
              int q = q0 + mt * 16 + g * 4 + rr;
#pragma unroll
              for (int nt = 0; nt < 4; nt++)
                if (k0 + nt * 16 + c > q) sv[mt][nt][rr] = -1e30f;
            }
        }

#pragma unroll
        for (int mt = 0; mt < 2; mt++)
#pragma unroll
          for (int rr = 0; rr < 4; rr++) {
            union { u16x4 u; bf16x4 h; } pw;
#pragma unroll
            for (int nt = 0; nt < 4; nt++)
              pw.h[nt] = (__bf16)__builtin_amdgcn_exp2f(sv[mt][nt][rr]);
            *(u16x4*)&P[wid][mt * 16 + g * 4 + rr][4 * c] = pw.u;
          }

        asm volatile("s_waitcnt lgkmcnt(0)" ::: "memory");

#pragma unroll
        for (int mt = 0; mt < 2; mt++) {
          bf16x8 pf0 = *(const bf16x8*)&P[wid][mt * 16 + c][g * 8];
          bf16x8 pf1 = *(const bf16x8*)&P[wid][mt * 16 + c][32 + g * 8];
          lac[mt] = MFMA(pf0, ones, lac[mt]);
          lac[mt] = MFMA(pf1, ones, lac[mt]);
#pragma unroll
          for (int ot = 0; ot < 4; ot++) {
            f32x4 oo = MFMA(pf0, vf[ot][0], o[mt][ot]);
            o[mt][ot] = MFMA(pf1, vf[ot][1], oo);
          }
        }
      }

      // ---- s2 = 1: fragment reads (before mid barrier) ----
      const int k0s1 = k0 + 64;
      const bool do1 = (k0s1 < kendw);  // wave-uniform
      bf16x8 kf1[4][2], vf1[4][2];
      if (do1) {
#pragma unroll
        for (int nt = 0; nt < 4; nt++)
#pragma unroll
          for (int h = 0; h < 2; h++) {
            kf1[nt][h] = *(const bf16x8*)&Ks[4096 + (nt * 2 + h) * 512 + lane * 8];
            vf1[nt][h] = *(const bf16x8*)&Vs[4096 + (nt * 2 + h) * 512 + lane * 8];
          }
      }
      __syncthreads();  // ALL waves' Ks/Vs reads complete -> buffer reusable

      // prefetch next tile into the same buffer; latency hides under the
      // s2=1 register-held compute below. Drained by next top-of-loop sync.
      if (kt + 1 < nkt) {
        const size_t kb = (size_t)(kt + 1) * 128 * 64;
#pragma unroll
        for (int r2 = 0; r2 < 4; r2++) {
          int idx = (r2 * 256 + tid) * 8;
          gld16(Kh + kb + idx, Ks + idx);
          gld16(Vh + kb + idx, Vs + idx);
        }
      }

      // ---- s2 = 1: compute from registers ----
      if (do1) {
        f32x4 sv[2][4];
#pragma unroll
        for (int mt = 0; mt < 2; mt++)
#pragma unroll
          for (int nt = 0; nt < 4; nt++) sv[mt][nt] = zero4;
#pragma unroll
        for (int nt = 0; nt < 4; nt++)
#pragma unroll
          for (int mt = 0; mt < 2; mt++) {
            sv[mt][nt] = MFMA(qf[mt][0], kf1[nt][0], sv[mt][nt]);
            sv[mt][nt] = MFMA(qf[mt][1], kf1[nt][1], sv[mt][nt]);
          }

        if (k0s1 + 64 > q0) {
#pragma unroll
          for (int mt = 0; mt < 2; mt++)
#pragma unroll
            for (int rr = 0; rr < 4; rr++) {
              int q = q0 + mt * 16 + g * 4 + rr;
#pragma unroll
              for (int nt = 0; nt < 4; nt++)
                if (k0s1 + nt * 16 + c > q) sv[mt][nt][rr] = -1e30f;
            }
        }

#pragma unroll
        for (int mt = 0; mt < 2; mt++)
#pragma unroll
          for (int rr = 0; rr < 4; rr++) {
            union { u16x4 u; bf16x4 h; } pw;
#pragma unroll
            for (int nt = 0; nt < 4; nt++)
              pw.h[nt] = (__bf16)__builtin_amdgcn_exp2f(sv[mt][nt][rr]);
            *(u16x4*)&P[wid][mt * 16 + g * 4 + rr][4 * c] = pw.u;
          }

        asm volatile("s_waitcnt lgkmcnt(0)" ::: "memory");

#pragma unroll
        for (int mt = 0; mt < 2; mt++) {
          bf16x8 pf0 = *(const bf16x8*)&P[wid][mt * 16 + c][g * 8];
          bf16x8 pf1 = *(const bf16x8*)&P[wid][mt * 16 + c][32 + g * 8];
          lac[mt] = MFMA(pf0, ones, lac[mt]);
          lac[mt] = MFMA(pf1, ones, lac[mt]);
#pragma unroll
          for (int ot = 0; ot < 4; ot++) {
            f32x4 oo = MFMA(pf0, vf1[ot][0], o[mt][ot]);
            o[mt][ot] = MFMA(pf1, vf1[ot][1], oo);
          }
        }
      }
    }

    float inv[2][4];
#pragma unroll
    for (int mt = 0; mt < 2; mt++)
#pragma unroll
      for (int rr = 0; rr < 4; rr++) inv[mt][rr] = 1.0f / lac[mt][rr];
#pragma unroll
    for (int mt = 0; mt < 2; mt++)
#pragma unroll
      for (int ot = 0; ot < 4; ot++)
#pragma unroll
        for (int rr = 0; rr < 4; rr++) {
          int t = q0 + mt * 16 + g * 4 + rr;
          int hd = ot * 16 + c;
          size_t xi = ((size_t)b * 2048 + t) * 1024 + head * 64 + hd;
          float v = x[xi] + o[mt][ot][rr] * inv[mt][rr];
          x1[xi] = v;
          xb1[xi] = f2b(v);
        }
  }
}

// ---------------------------------------------------------------------------
extern "C" void kernel_launch(void* const* d_in, const int* in_sizes, int n_in,
                              void* d_out, int out_size, void* d_ws, size_t ws_size,
                              hipStream_t stream) {
  (void)in_sizes; (void)n_in; (void)out_size; (void)ws_size;
  const float* x = (const float*)d_in[0];
  const float* Wq = (const float*)d_in[1];
  const float* bq = (const float*)d_in[2];
  const float* Wk = (const float*)d_in[3];
  const float* bk = (const float*)d_in[4];
  const float* Wv = (const float*)d_in[5];
  const float* bv = (const float*)d_in[6];
  const float* W1 = (const float*)d_in[7];
  const float* b1 = (const float*)d_in[8];
  const float* W2 = (const float*)d_in[9];
  const float* b2 = (const float*)d_in[10];

  char* ws = (char*)d_ws;
  size_t off = 0;
  auto alloc = [&](size_t bytes) {
    char* p = ws + off;
    off += (bytes + 255) & ~(size_t)255;
    return p;
  };
  u16* xb    = (u16*)alloc(8192ull * 1024 * 2);   // bf16(x)
  u16* Wqkvt = (u16*)alloc(3072ull * 1024 * 2);   // [3072][1024] bf16 (Wq|Wk|Wv rows)
  u16* W1t   = (u16*)alloc(4096ull * 1024 * 2);
  u16* W2t   = (u16*)alloc(1024ull * 4096 * 2);
  u16* Qb    = (u16*)alloc(3ull * 8192 * 1024 * 2);  // Q|K|V frag-ordered, contiguous
  float* x1  = (float*)alloc(8192ull * 1024 * 4); // x + attn (fp32 residual)
  u16* hb    = (u16*)alloc(8192ull * 4096 * 2);   // gelu(x1@W1+b1)
  u16* xb1   = xb;  // xb dead after QKV gemm; reuse for bf16(x1)
  u16* Kb    = Qb + 8388608;
  u16* Vtb   = Qb + 16777216;

  const float qscale = 1.4426950408889634f / 32.0f;  // log2e / sqrt(H)

  // 1. prep: x -> bf16 + all weight transposes, ONE launch
  prep<<<dim3(19456), dim3(32, 8), 0, stream>>>(
      x, xb, Wq, Wk, Wv, W1, W2, Wqkvt, W1t, W2t);
  // 2. fused QKV projection (M=8192, N=3072, K=1024) -> frag-ordered Q/K/V
  gemm256<4><<<dim3(768), dim3(512), 0, stream>>>(
      xb, Wqkvt, bq, bk, bv, Qb, nullptr, 3072, 1024, qscale);
  // 3. attention + residual 1  (512 blocks; paired 128-row tiles)
  attn_kernel<<<dim3(512), dim3(256), 0, stream>>>(Qb, Kb, Vtb, x, x1, xb1);
  // 4. MLP1: gelu(x1 @ W1 + b1): 256x256 8-phase counted (512 blocks, R7)
  gemm8p<2><<<dim3(512), dim3(512), 0, stream>>>(
      xb1, W1t, b1, hb, 4096, 1024);
  // 5. MLP2 + residual 2 -> d_out (fp32): 256 blocks, 64 K-tiles
  gemm256<3><<<dim3(256), dim3(512), 0, stream>>>(
      hb, W2t, b2, nullptr, nullptr, d_out, x1, 1024, 4096, 1.0f);
}